// Round 1
// baseline (596.351 us; speedup 1.0000x reference)
//
#include <hip/hip_runtime.h>
#include <hip/hip_bf16.h>

// DepthEmissionRaymarcher: per-ray absorption compositing.
//   d[p] = density (wall: d[P-1]=1), cum = min(cumsum(d),1),
//   probs = diff(cum), depth = sum(probs*len), feat = sum(probs*f).
// Key fact: probs are EXACTLY 0 once cum saturates at 1 (densities >= 0),
// so we scan sequentially and break — expected ~3 of 128 samples touched.

#define RM_P 128
#define RM_F 8

__global__ __launch_bounds__(256) void DepthEmissionRaymarcher_9904194584773_kernel(
    const float* __restrict__ dens,   // (R, P)
    const float* __restrict__ feat,   // (R, P, F)
    const float* __restrict__ len,    // (R, P)
    float* __restrict__ out_depth,    // (R)
    float* __restrict__ out_feat,     // (R, F)
    int n_rays)
{
    int ray = blockIdx.x * blockDim.x + threadIdx.x;
    if (ray >= n_rays) return;

    const float*  d  = dens + (long)ray * RM_P;
    const float*  l  = len  + (long)ray * RM_P;
    const float4* fr = (const float4*)(feat + (long)ray * RM_P * RM_F);

    float  cum   = 0.0f;
    float  depth = 0.0f;
    float4 acc0  = make_float4(0.f, 0.f, 0.f, 0.f);
    float4 acc1  = make_float4(0.f, 0.f, 0.f, 0.f);

    #pragma unroll 1
    for (int p = 0; p < RM_P; ++p) {
        float dd   = (p == RM_P - 1) ? 1.0f : d[p];
        float ncum = cum + dd;
        if (ncum > 1.0f) ncum = 1.0f;
        float prob = ncum - cum;
        cum = ncum;

        depth = fmaf(prob, l[p], depth);
        float4 f0 = fr[2 * p];
        float4 f1 = fr[2 * p + 1];
        acc0.x = fmaf(prob, f0.x, acc0.x);
        acc0.y = fmaf(prob, f0.y, acc0.y);
        acc0.z = fmaf(prob, f0.z, acc0.z);
        acc0.w = fmaf(prob, f0.w, acc0.w);
        acc1.x = fmaf(prob, f1.x, acc1.x);
        acc1.y = fmaf(prob, f1.y, acc1.y);
        acc1.z = fmaf(prob, f1.z, acc1.z);
        acc1.w = fmaf(prob, f1.w, acc1.w);

        if (cum >= 1.0f) break;   // all remaining probs exactly 0
    }

    out_depth[ray] = depth;
    float4* of = (float4*)(out_feat + (long)ray * RM_F);
    of[0] = acc0;
    of[1] = acc1;
}

extern "C" void kernel_launch(void* const* d_in, const int* in_sizes, int n_in,
                              void* d_out, int out_size, void* d_ws, size_t ws_size,
                              hipStream_t stream) {
    const float* dens = (const float*)d_in[0];  // (B,H,W,P,1)
    const float* feat = (const float*)d_in[1];  // (B,H,W,P,F)
    const float* len  = (const float*)d_in[2];  // (B,H,W,P)

    const int n_rays = in_sizes[2] / RM_P;      // B*H*W = 122880

    float* out_depth = (float*)d_out;           // first R floats
    float* out_feat  = out_depth + n_rays;      // then R*F floats

    dim3 block(256);
    dim3 grid((n_rays + 255) / 256);
    DepthEmissionRaymarcher_9904194584773_kernel<<<grid, block, 0, stream>>>(
        dens, feat, len, out_depth, out_feat, n_rays);
}

// Round 2
// 590.164 us; speedup vs baseline: 1.0105x; 1.0105x over previous
//
#include <hip/hip_runtime.h>
#include <hip/hip_bf16.h>

// DepthEmissionRaymarcher: per-ray absorption compositing.
//   d[p] = density (wall: d[P-1]=1), cum = min(cumsum(d),1) (== running
//   min(cum+d,1) since d>=0), probs = diff(cum),
//   depth = sum(probs*len), feat = sum(probs*f).
// probs are EXACTLY 0 once cum saturates; densities ~U[0,1] so saturation
// is at sample ~3.  Strategy: batch samples 4-at-a-time with independent
// float4 loads (one latency exposure, not a serial dependent-load chain).
// First batch covers 96% of rays; divergent batched tail covers the rest.

#define RM_P 128
#define RM_F 8

__global__ __launch_bounds__(256) void DepthEmissionRaymarcher_9904194584773_kernel(
    const float* __restrict__ dens,   // (R, P)
    const float* __restrict__ feat,   // (R, P, F)
    const float* __restrict__ len,    // (R, P)
    float* __restrict__ out_depth,    // (R)
    float* __restrict__ out_feat,     // (R, F)
    int n_rays)
{
    int ray = blockIdx.x * blockDim.x + threadIdx.x;
    if (ray >= n_rays) return;

    const float4* d4 = (const float4*)(dens + (long)ray * RM_P);
    const float4* l4 = (const float4*)(len  + (long)ray * RM_P);
    const float4* fr = (const float4*)(feat + (long)ray * RM_P * RM_F);

    float  depth = 0.0f;
    float4 acc0  = make_float4(0.f, 0.f, 0.f, 0.f);
    float4 acc1  = make_float4(0.f, 0.f, 0.f, 0.f);
    float  cum   = 0.0f;

    // ---- batch 0: samples 0..3, all loads independent, issued together ----
    {
        float4 dv = d4[0];
        float4 lv = l4[0];
        float4 f0a = fr[0], f0b = fr[1];
        float4 f1a = fr[2], f1b = fr[3];
        float4 f2a = fr[4], f2b = fr[5];
        float4 f3a = fr[6], f3b = fr[7];

        float c0 = fminf(dv.x,            1.0f);
        float c1 = fminf(c0 + dv.y,       1.0f);
        float c2 = fminf(c1 + dv.z,       1.0f);
        float c3 = fminf(c2 + dv.w,       1.0f);
        float p0 = c0;
        float p1 = c1 - c0;
        float p2 = c2 - c1;
        float p3 = c3 - c2;
        cum = c3;

        depth = p0*lv.x + p1*lv.y + p2*lv.z + p3*lv.w;

        acc0.x = p0*f0a.x + p1*f1a.x + p2*f2a.x + p3*f3a.x;
        acc0.y = p0*f0a.y + p1*f1a.y + p2*f2a.y + p3*f3a.y;
        acc0.z = p0*f0a.z + p1*f1a.z + p2*f2a.z + p3*f3a.z;
        acc0.w = p0*f0a.w + p1*f1a.w + p2*f2a.w + p3*f3a.w;
        acc1.x = p0*f0b.x + p1*f1b.x + p2*f2b.x + p3*f3b.x;
        acc1.y = p0*f0b.y + p1*f1b.y + p2*f2b.y + p3*f3b.y;
        acc1.z = p0*f0b.z + p1*f1b.z + p2*f2b.z + p3*f3b.z;
        acc1.w = p0*f0b.w + p1*f1b.w + p2*f2b.w + p3*f3b.w;
    }

    // ---- tail: batches 1..31 (rare: P(needed) ~ 4% per ray) ----
    #pragma unroll 1
    for (int b = 1; b < RM_P / 4; ++b) {
        if (cum >= 1.0f) break;           // all remaining probs exactly 0

        float4 dv = d4[b];
        float4 lv = l4[b];
        if (b == RM_P / 4 - 1) dv.w = 1.0f;   // wall: force last density to 1

        float4 fa0 = fr[8*b + 0], fb0 = fr[8*b + 1];
        float4 fa1 = fr[8*b + 2], fb1 = fr[8*b + 3];
        float4 fa2 = fr[8*b + 4], fb2 = fr[8*b + 5];
        float4 fa3 = fr[8*b + 6], fb3 = fr[8*b + 7];

        float c0 = fminf(cum + dv.x, 1.0f);
        float c1 = fminf(c0  + dv.y, 1.0f);
        float c2 = fminf(c1  + dv.z, 1.0f);
        float c3 = fminf(c2  + dv.w, 1.0f);
        float p0 = c0 - cum;
        float p1 = c1 - c0;
        float p2 = c2 - c1;
        float p3 = c3 - c2;
        cum = c3;

        depth += p0*lv.x + p1*lv.y + p2*lv.z + p3*lv.w;

        acc0.x += p0*fa0.x + p1*fa1.x + p2*fa2.x + p3*fa3.x;
        acc0.y += p0*fa0.y + p1*fa1.y + p2*fa2.y + p3*fa3.y;
        acc0.z += p0*fa0.z + p1*fa1.z + p2*fa2.z + p3*fa3.z;
        acc0.w += p0*fa0.w + p1*fa1.w + p2*fa2.w + p3*fa3.w;
        acc1.x += p0*fb0.x + p1*fb1.x + p2*fb2.x + p3*fb3.x;
        acc1.y += p0*fb0.y + p1*fb1.y + p2*fb2.y + p3*fb3.y;
        acc1.z += p0*fb0.z + p1*fb1.z + p2*fb2.z + p3*fb3.z;
        acc1.w += p0*fb0.w + p1*fb1.w + p2*fb2.w + p3*fb3.w;
    }

    out_depth[ray] = depth;
    float4* of = (float4*)(out_feat + (long)ray * RM_F);
    of[0] = acc0;
    of[1] = acc1;
}

extern "C" void kernel_launch(void* const* d_in, const int* in_sizes, int n_in,
                              void* d_out, int out_size, void* d_ws, size_t ws_size,
                              hipStream_t stream) {
    const float* dens = (const float*)d_in[0];  // (B,H,W,P,1)
    const float* feat = (const float*)d_in[1];  // (B,H,W,P,F)
    const float* len  = (const float*)d_in[2];  // (B,H,W,P)

    const int n_rays = in_sizes[2] / RM_P;      // B*H*W = 122880

    float* out_depth = (float*)d_out;           // first R floats
    float* out_feat  = out_depth + n_rays;      // then R*F floats

    dim3 block(256);
    dim3 grid((n_rays + 255) / 256);
    DepthEmissionRaymarcher_9904194584773_kernel<<<grid, block, 0, stream>>>(
        dens, feat, len, out_depth, out_feat, n_rays);
}